// Round 16
// baseline (62.459 us; speedup 1.0000x reference)
//
#include <hip/hip_runtime.h>
#include <hip/hip_bf16.h>
#include <math.h>

// logits [8,19,256,512] f32, targets [8,256,512] int32
// R=20 truncated EDT, loss = mean_b sum_c mean_hw probs*sdf
#define NCLS 19
#define BB   8
#define HH   256
#define WW   512
#define CAP2 400u     // R^2; any value >= 400 caps identically
#define SEG  8        // rows per kA segment
#define WPC  70       // uint4 per class row in LDS (280 dwords: halo12+256+halo12)

typedef unsigned short u16x2 __attribute__((ext_vector_type(2)));

static __device__ __forceinline__ unsigned umin32(unsigned a, unsigned b) { return a < b ? a : b; }
static __device__ __forceinline__ float fsqrt_fast(float x) { return __builtin_amdgcn_sqrtf(x); }

static __device__ __forceinline__ unsigned pk_add_s(unsigned v, unsigned c) {
    unsigned d; asm("v_pk_add_u16 %0, %1, %2" : "=v"(d) : "s"(c), "v"(v)); return d;
}
static __device__ __forceinline__ unsigned pk_minv(unsigned a, unsigned b) {
    unsigned d; asm("v_pk_min_u16 %0, %1, %2" : "=v"(d) : "v"(a), "v"(b)); return d;
}
static __device__ __forceinline__ unsigned pk_maxv(unsigned a, unsigned b) {
    unsigned d; asm("v_pk_max_u16 %0, %1, %2" : "=v"(d) : "v"(a), "v"(b)); return d;
}
static __device__ __forceinline__ unsigned pk_hmin(unsigned a) {
    unsigned d;
    asm("v_pk_min_u16 %0, %1, %1 op_sel:[1,0] op_sel_hi:[0,1]" : "=v"(d) : "v"(a));
    return d;
}
// 4 u8 distances in x -> two packed-u16 squared words (verified r5)
static __device__ __forceinline__ void sq8(unsigned x, unsigned& w0, unsigned& w1) {
    unsigned a = x & 0x00FF00FFu;
    unsigned b = (x >> 8) & 0x00FF00FFu;
    u16x2 sa = __builtin_bit_cast(u16x2, a); sa = sa * sa;
    u16x2 sb = __builtin_bit_cast(u16x2, b); sb = sb * sb;
    unsigned ua = __builtin_bit_cast(unsigned, sa);
    unsigned ub = __builtin_bit_cast(unsigned, sb);
    w0 = __builtin_amdgcn_perm(ub, ua, 0x05040100u);
    w1 = __builtin_amdgcn_perm(ub, ua, 0x07060302u);
}

// ---------------------------------------------------------------------------
// Kernel A: vertical pass, SEG=8, u8 output (verified, ~13us).
// Block 0 lanes 0..63 zero the 64 accumulator cells.
// ---------------------------------------------------------------------------
__global__ __launch_bounds__(256)
void kA_vert(const int* __restrict__ targ, unsigned char* __restrict__ vneg,
             unsigned long long* __restrict__ acc) {
    if (blockIdx.x == 0 && threadIdx.x < 64) acc[threadIdx.x] = 0ULL;
    int gid = blockIdx.x * 256 + threadIdx.x;  // 4096 cols * 32 segs = 131072
    int col = gid & 4095;
    int seg = gid >> 12;
    int b = col >> 9;
    int w = col & 511;
    int h0 = seg * SEG;
    const int* tp = &targ[b * HH * WW + w];

    unsigned d[NCLS];
    unsigned pk[NCLS][2];
#pragma unroll
    for (int c = 0; c < NCLS; ++c) { d[c] = 21u; pk[c][0] = 0u; pk[c][1] = 0u; }
#pragma unroll
    for (int k = 0; k < 21 + SEG; ++k) {
        int hh = h0 - 21 + k;
        int t = -1;
        if (hh >= 0) t = tp[hh * WW];
#pragma unroll
        for (int c = 0; c < NCLS; ++c)
            d[c] = (t == c) ? 0u : d[c] + 1u;
        if (k >= 21) {
            int r = k - 21;
#pragma unroll
            for (int c = 0; c < NCLS; ++c)
                pk[c][r >> 2] |= d[c] << ((r & 3) * 8);
        }
    }
    unsigned u[NCLS];
#pragma unroll
    for (int c = 0; c < NCLS; ++c) u[c] = 21u;
#pragma unroll
    for (int k = 0; k < 21 + SEG; ++k) {
        int hh = h0 + 21 + SEG - 1 - k;
        int t = -1;
        if (hh < HH) t = tp[hh * WW];
#pragma unroll
        for (int c = 0; c < NCLS; ++c)
            u[c] = (t == c) ? 0u : u[c] + 1u;
        if (k >= 21) {
            int r = 21 + SEG - 1 - k;
#pragma unroll
            for (int c = 0; c < NCLS; ++c) {
                unsigned dv = (pk[c][r >> 2] >> ((r & 3) * 8)) & 0xffu;
                vneg[((size_t)(b * NCLS + c) * HH + hh) * WW + w] =
                    (unsigned char)umin32(dv, u[c]);
            }
        }
    }
}

// ---------------------------------------------------------------------------
// Kernel B1: horizontal EDT only. ONE WAVE per (row, class): 38912
// independent waves, no class loop, no merge, no barriers. Stage own row
// (u16 squares, halo12+256+halo12 dwords) to LDS; 7 ds_read_b128 window
// (3 upfront + 4 in the ~15% vote-fail branch); cascade exact. Writes
// min(nd^2,400) u16 (cap commutes with min; sqrt monotone; nd==0 exact).
// ---------------------------------------------------------------------------
__global__ __launch_bounds__(256)
void kB1_horiz(const unsigned char* __restrict__ vneg,
               unsigned short* __restrict__ nd2) {
    __shared__ __align__(16) unsigned smem[4 * 280];   // 4480 B
    int tid = threadIdx.x;
    int L = tid & 63;
    int wid = tid >> 6;
    int c = blockIdx.x;                 // 0..18
    int bh = blockIdx.y * 4 + wid;      // 0..2047
    int b = bh >> 8;
    int h = bh & 255;

#define SQx(x) ((unsigned)((x) * (x)))
#define PK2(a, bq) (SQx(a) | (SQx(bq) << 16))
    const unsigned CE[21] = {
        PK2(-20,-19), PK2(-18,-17), PK2(-16,-15), PK2(-14,-13), PK2(-12,-11),
        PK2(-10,-9),  PK2(-8,-7),   PK2(-6,-5),   PK2(-4,-3),   PK2(-2,-1),
        PK2(0,1),     PK2(2,3),     PK2(4,5),     PK2(6,7),     PK2(8,9),
        PK2(10,11),   PK2(12,13),   PK2(14,15),   PK2(16,17),   PK2(18,19),
        PK2(20,21) };
    const unsigned CO[21] = {
        PK2(-21,-20), PK2(-19,-18), PK2(-17,-16), PK2(-15,-14), PK2(-13,-12),
        PK2(-11,-10), PK2(-9,-8),   PK2(-7,-6),   PK2(-5,-4),   PK2(-3,-2),
        PK2(-1,0),    PK2(1,2),     PK2(3,4),     PK2(5,6),     PK2(7,8),
        PK2(9,10),    PK2(11,12),   PK2(13,14),   PK2(15,16),   PK2(17,18),
        PK2(19,20) };
#undef PK2
#undef SQx

    const unsigned HALO2 = 441u | (441u << 16);
    size_t rowoff = (size_t)(b * NCLS + c) * HH + h;

    // wave-local stage (same-wave ds_write -> ds_read, lgkmcnt-ordered)
    uint2 v8 = ((const uint2*)vneg)[rowoff * 64 + L];
    uint4 wq;
    sq8(v8.x, wq.x, wq.y);
    sq8(v8.y, wq.z, wq.w);
    unsigned* srow = smem + wid * 280;
    ((uint4*)srow)[L + 3] = wq;                // dwords k=4L+12..4L+15
    if (L < 12) srow[L] = HALO2;               // k=0..11
    if (L >= 52) srow[216 + L] = HALO2;        // k=268..279

    // center window: q2,q3,q4 = dwords W[8..19] (taps m=7..13 need W[9..18])
    const uint4* basep = (const uint4*)srow + L;
    uint4 q2 = basep[2], q3 = basep[3], q4 = basep[4];
    unsigned W[28];
    W[8]=q2.x;  W[9]=q2.y;  W[10]=q2.z; W[11]=q2.w;
    W[12]=q3.x; W[13]=q3.y; W[14]=q3.z; W[15]=q3.w;
    W[16]=q4.x; W[17]=q4.y; W[18]=q4.z; W[19]=q4.w;

    unsigned ae[4], ao[4];
#pragma unroll
    for (int r = 0; r < 4; ++r) { ae[r] = 0xFFFFFFFFu; ao[r] = 0xFFFFFFFFu; }

#pragma unroll
    for (int r = 0; r < 4; ++r)
#pragma unroll
        for (int m = 7; m <= 13; ++m) {
            ae[r] = pk_minv(ae[r], pk_add_s(W[r + m + 2], CE[m]));
            ao[r] = pk_minv(ao[r], pk_add_s(W[r + m + 2], CO[m]));
        }

    unsigned mx = pk_maxv(pk_maxv(pk_maxv(pk_hmin(ae[0]), pk_hmin(ao[0])),
                                  pk_maxv(pk_hmin(ae[1]), pk_hmin(ao[1]))),
                          pk_maxv(pk_maxv(pk_hmin(ae[2]), pk_hmin(ao[2])),
                                  pk_maxv(pk_hmin(ae[3]), pk_hmin(ao[3]))));
    if (!__all(mx <= (49u | (49u << 16)))) {
        uint4 q0 = basep[0], q1 = basep[1], q5 = basep[5], q6 = basep[6];
        W[0]=q0.x;  W[1]=q0.y;  W[2]=q0.z;  W[3]=q0.w;
        W[4]=q1.x;  W[5]=q1.y;  W[6]=q1.z;  W[7]=q1.w;
        W[20]=q5.x; W[21]=q5.y; W[22]=q5.z; W[23]=q5.w;
        W[24]=q6.x; W[25]=q6.y; W[26]=q6.z; W[27]=q6.w;
#pragma unroll
        for (int r = 0; r < 4; ++r) {
#pragma unroll
            for (int m = 0; m <= 6; ++m) {
                ae[r] = pk_minv(ae[r], pk_add_s(W[r + m + 2], CE[m]));
                ao[r] = pk_minv(ao[r], pk_add_s(W[r + m + 2], CO[m]));
            }
#pragma unroll
            for (int m = 14; m <= 20; ++m) {
                ae[r] = pk_minv(ae[r], pk_add_s(W[r + m + 2], CE[m]));
                ao[r] = pk_minv(ao[r], pk_add_s(W[r + m + 2], CO[m]));
            }
        }
    }

    // pack 8 capped u16 results, one dwordx4 store (coalesced)
    uint4 outq;
    unsigned o[4];
#pragma unroll
    for (int r = 0; r < 4; ++r) {
        unsigned nd0 = umin32(pk_hmin(ae[r]) & 0xFFFFu, CAP2);
        unsigned nd1 = umin32(pk_hmin(ao[r]) & 0xFFFFu, CAP2);
        o[r] = nd0 | (nd1 << 16);
    }
    outq.x = o[0]; outq.y = o[1]; outq.z = o[2]; outq.w = o[3];
    ((uint4*)nd2)[rowoff * 64 + L] = outq;     // px 8L..8L+7
}

// ---------------------------------------------------------------------------
// Kernel B2: pure streaming softmax+loss. 4 px/thread, 19 coalesced
// float4(logits) + ushort4(nd2) loads. Targets-free epilogue (nd==0 marks
// the target class). BW-bound: 120 MB read. Scatter-atomic (64 cells,
// integer = deterministic). No fences.
// ---------------------------------------------------------------------------
__global__ __launch_bounds__(256)
void kB2_loss(const float* __restrict__ logits,
              const unsigned short* __restrict__ nd2,
              unsigned long long* __restrict__ acc) {
    __shared__ float wsum[4];
    int tid = threadIdx.x;
    int g = blockIdx.x * 256 + tid;     // 0..262143 (4-px groups)
    int b = g >> 15;                    // 32768 groups per batch
    int rem = g & 32767;
    int h = rem >> 7;                   // 128 groups per row
    int w = (rem & 127) * 4;
    size_t base = ((size_t)(b * NCLS) * HH + h) * WW + w;

    float den[4] = {0,0,0,0}, num[4] = {0,0,0,0}, et[4] = {0,0,0,0};
    unsigned m2[4] = {0xFFFFu, 0xFFFFu, 0xFFFFu, 0xFFFFu};

#pragma unroll 1
    for (int c = 0; c < NCLS; ++c) {
        size_t off = base + (size_t)c * (HH * WW);
        float4 lg = *(const float4*)(logits + off);
        ushort4 nd = *(const ushort4*)(nd2 + off);
        float lgs[4] = {lg.x, lg.y, lg.z, lg.w};
        unsigned nds[4] = {nd.x, nd.y, nd.z, nd.w};
#pragma unroll
        for (int k = 0; k < 4; ++k) {
            float e = __expf(lgs[k]);
            den[k] += e;
            num[k] += e * fsqrt_fast((float)nds[k]);   // nd==0 -> adds 0
            bool z = (nds[k] == 0);
            et[k] = z ? e : et[k];
            m2[k] = umin32(m2[k], z ? 0xFFFFu : nds[k]);
        }
    }

    float v = 0.f;
#pragma unroll
    for (int k = 0; k < 4; ++k)
        v += (num[k] - et[k] * fsqrt_fast((float)umin32(m2[k], CAP2))) / den[k];

#pragma unroll
    for (int off = 32; off >= 1; off >>= 1) v += __shfl_down(v, off);
    int L = tid & 63, wid = tid >> 6;
    if (L == 0) wsum[wid] = v;
    __syncthreads();
    if (tid == 0) {
        float s = (wsum[0] + wsum[1]) + (wsum[2] + wsum[3]);
        // fixed-point 2^36 with /20 folded in; integer atomic => deterministic
        double q = (double)s * (68719476736.0 / 20.0);
        atomicAdd(&acc[blockIdx.x & 63], (unsigned long long)(long long)q);
    }
}

__global__ void kC_final(const unsigned long long* __restrict__ acc,
                         float* __restrict__ out) {
    long long iv = 0;
    for (int i = 0; i < 64; ++i) iv += (long long)acc[i];
    double v = (double)iv / 68719476736.0;
    out[0] = (float)(v / (double)((size_t)BB * HH * WW));
}

extern "C" void kernel_launch(void* const* d_in, const int* in_sizes, int n_in,
                              void* d_out, int out_size, void* d_ws, size_t ws_size,
                              hipStream_t stream) {
    const float* logits = (const float*)d_in[0];
    const int* targ = (const int*)d_in[1];
    unsigned char* wsb = (unsigned char*)d_ws;
    unsigned long long* acc = (unsigned long long*)wsb;       // [0,512): 64 cells
    unsigned char* vneg = wsb + 1024;                         // 19.9 MB u8
    unsigned short* nd2 = (unsigned short*)(wsb + 1024 + 20971520); // 39.8 MB u16

    kA_vert<<<512, 256, 0, stream>>>(targ, vneg, acc);        // zeroes acc[64]
    kB1_horiz<<<dim3(NCLS, 512), 256, 0, stream>>>(vneg, nd2);
    kB2_loss<<<1024, 256, 0, stream>>>(logits, nd2, acc);
    kC_final<<<1, 1, 0, stream>>>(acc, (float*)d_out);
}

// Round 17
// 58.010 us; speedup vs baseline: 1.0767x; 1.0767x over previous
//
#include <hip/hip_runtime.h>
#include <hip/hip_bf16.h>
#include <math.h>

// logits [8,19,256,512] f32, targets [8,256,512] int32
// R=20 truncated EDT, loss = mean_b sum_c mean_hw probs*sdf
#define NCLS 19
#define BB   8
#define HH   256
#define WW   512
#define CAP2 400u     // R^2; any value >= 400 caps identically
#define SEG  8        // rows per kA segment
#define WPC  70       // uint4 per class row in LDS (280 dwords: halo12+256+halo12)

typedef unsigned short u16x2 __attribute__((ext_vector_type(2)));

static __device__ __forceinline__ unsigned umin32(unsigned a, unsigned b) { return a < b ? a : b; }
static __device__ __forceinline__ float fsqrt_fast(float x) { return __builtin_amdgcn_sqrtf(x); }

static __device__ __forceinline__ unsigned pk_add_s(unsigned v, unsigned c) {
    unsigned d; asm("v_pk_add_u16 %0, %1, %2" : "=v"(d) : "s"(c), "v"(v)); return d;
}
static __device__ __forceinline__ unsigned pk_minv(unsigned a, unsigned b) {
    unsigned d; asm("v_pk_min_u16 %0, %1, %2" : "=v"(d) : "v"(a), "v"(b)); return d;
}
static __device__ __forceinline__ unsigned pk_maxv(unsigned a, unsigned b) {
    unsigned d; asm("v_pk_max_u16 %0, %1, %2" : "=v"(d) : "v"(a), "v"(b)); return d;
}
static __device__ __forceinline__ unsigned pk_hmin(unsigned a) {
    unsigned d;
    asm("v_pk_min_u16 %0, %1, %1 op_sel:[1,0] op_sel_hi:[0,1]" : "=v"(d) : "v"(a));
    return d;
}
// 4 u8 distances in x -> two packed-u16 squared words (verified r5)
static __device__ __forceinline__ void sq8(unsigned x, unsigned& w0, unsigned& w1) {
    unsigned a = x & 0x00FF00FFu;
    unsigned b = (x >> 8) & 0x00FF00FFu;
    u16x2 sa = __builtin_bit_cast(u16x2, a); sa = sa * sa;
    u16x2 sb = __builtin_bit_cast(u16x2, b); sb = sb * sb;
    unsigned ua = __builtin_bit_cast(unsigned, sa);
    unsigned ub = __builtin_bit_cast(unsigned, sb);
    w0 = __builtin_amdgcn_perm(ub, ua, 0x05040100u);
    w1 = __builtin_amdgcn_perm(ub, ua, 0x07060302u);
}

// ---- kB helpers: force-inlined so the pair body is ONE scheduling region ----
static __device__ __forceinline__ void center_band(const uint4* basep, unsigned W[28],
        unsigned ae[4], unsigned ao[4], const unsigned CE[21], const unsigned CO[21]) {
    uint4 q2 = basep[2], q3 = basep[3], q4 = basep[4];
    W[8]=q2.x;  W[9]=q2.y;  W[10]=q2.z; W[11]=q2.w;
    W[12]=q3.x; W[13]=q3.y; W[14]=q3.z; W[15]=q3.w;
    W[16]=q4.x; W[17]=q4.y; W[18]=q4.z; W[19]=q4.w;
#pragma unroll
    for (int r = 0; r < 4; ++r) { ae[r] = 0xFFFFFFFFu; ao[r] = 0xFFFFFFFFu; }
#pragma unroll
    for (int r = 0; r < 4; ++r)
#pragma unroll
        for (int m = 7; m <= 13; ++m) {
            ae[r] = pk_minv(ae[r], pk_add_s(W[r + m + 2], CE[m]));
            ao[r] = pk_minv(ao[r], pk_add_s(W[r + m + 2], CO[m]));
        }
}
static __device__ __forceinline__ unsigned vote8(const unsigned ae[4], const unsigned ao[4]) {
    return pk_maxv(pk_maxv(pk_maxv(pk_hmin(ae[0]), pk_hmin(ao[0])),
                           pk_maxv(pk_hmin(ae[1]), pk_hmin(ao[1]))),
                   pk_maxv(pk_maxv(pk_hmin(ae[2]), pk_hmin(ao[2])),
                           pk_maxv(pk_hmin(ae[3]), pk_hmin(ao[3]))));
}
static __device__ __forceinline__ void outer_band(const uint4* basep, unsigned W[28],
        unsigned ae[4], unsigned ao[4], const unsigned CE[21], const unsigned CO[21]) {
    uint4 q0 = basep[0], q1 = basep[1], q5 = basep[5], q6 = basep[6];
    W[0]=q0.x;  W[1]=q0.y;  W[2]=q0.z;  W[3]=q0.w;
    W[4]=q1.x;  W[5]=q1.y;  W[6]=q1.z;  W[7]=q1.w;
    W[20]=q5.x; W[21]=q5.y; W[22]=q5.z; W[23]=q5.w;
    W[24]=q6.x; W[25]=q6.y; W[26]=q6.z; W[27]=q6.w;
#pragma unroll
    for (int r = 0; r < 4; ++r) {
#pragma unroll
        for (int m = 0; m <= 6; ++m) {
            ae[r] = pk_minv(ae[r], pk_add_s(W[r + m + 2], CE[m]));
            ao[r] = pk_minv(ao[r], pk_add_s(W[r + m + 2], CO[m]));
        }
#pragma unroll
        for (int m = 14; m <= 20; ++m) {
            ae[r] = pk_minv(ae[r], pk_add_s(W[r + m + 2], CE[m]));
            ao[r] = pk_minv(ao[r], pk_add_s(W[r + m + 2], CO[m]));
        }
    }
}
static __device__ __forceinline__ void epilogue(const unsigned ae[4], const unsigned ao[4],
        float4 f0, float4 f1, float den[8], float num[8], float et[8], unsigned m2[8]) {
    float fx[8] = {f0.x, f0.y, f0.z, f0.w, f1.x, f1.y, f1.z, f1.w};
#pragma unroll
    for (int r = 0; r < 4; ++r) {
        unsigned nd0 = pk_hmin(ae[r]) & 0xFFFFu;   // px 8L+2r
        unsigned nd1 = pk_hmin(ao[r]) & 0xFFFFu;   // px 8L+2r+1
        float e0 = __expf(fx[2 * r]), e1 = __expf(fx[2 * r + 1]);
        den[2 * r] += e0; den[2 * r + 1] += e1;
        float s0 = fsqrt_fast((float)umin32(nd0, CAP2));
        float s1 = fsqrt_fast((float)umin32(nd1, CAP2));
        num[2 * r]     += e0 * s0;     // target term: e*sqrt(0)=0, self-excluded
        num[2 * r + 1] += e1 * s1;
        bool z0 = (nd0 == 0), z1 = (nd1 == 0);
        et[2 * r]     = z0 ? e0 : et[2 * r];
        et[2 * r + 1] = z1 ? e1 : et[2 * r + 1];
        m2[2 * r]     = umin32(m2[2 * r],     z0 ? 0xFFFFu : nd0);
        m2[2 * r + 1] = umin32(m2[2 * r + 1], z1 ? 0xFFFFu : nd1);
    }
}

// ---------------------------------------------------------------------------
// Kernel A: vertical pass, SEG=8, u8 output (verified, ~13us).
// Block 0 lanes 0..63 zero the 64 accumulator cells.
// ---------------------------------------------------------------------------
__global__ __launch_bounds__(256)
void kA_vert(const int* __restrict__ targ, unsigned char* __restrict__ vneg,
             unsigned long long* __restrict__ acc) {
    if (blockIdx.x == 0 && threadIdx.x < 64) acc[threadIdx.x] = 0ULL;
    int gid = blockIdx.x * 256 + threadIdx.x;  // 4096 cols * 32 segs = 131072
    int col = gid & 4095;
    int seg = gid >> 12;
    int b = col >> 9;
    int w = col & 511;
    int h0 = seg * SEG;
    const int* tp = &targ[b * HH * WW + w];

    unsigned d[NCLS];
    unsigned pk[NCLS][2];
#pragma unroll
    for (int c = 0; c < NCLS; ++c) { d[c] = 21u; pk[c][0] = 0u; pk[c][1] = 0u; }
#pragma unroll
    for (int k = 0; k < 21 + SEG; ++k) {
        int hh = h0 - 21 + k;
        int t = -1;
        if (hh >= 0) t = tp[hh * WW];
#pragma unroll
        for (int c = 0; c < NCLS; ++c)
            d[c] = (t == c) ? 0u : d[c] + 1u;
        if (k >= 21) {
            int r = k - 21;
#pragma unroll
            for (int c = 0; c < NCLS; ++c)
                pk[c][r >> 2] |= d[c] << ((r & 3) * 8);
        }
    }
    unsigned u[NCLS];
#pragma unroll
    for (int c = 0; c < NCLS; ++c) u[c] = 21u;
#pragma unroll
    for (int k = 0; k < 21 + SEG; ++k) {
        int hh = h0 + 21 + SEG - 1 - k;
        int t = -1;
        if (hh < HH) t = tp[hh * WW];
#pragma unroll
        for (int c = 0; c < NCLS; ++c)
            u[c] = (t == c) ? 0u : u[c] + 1u;
        if (k >= 21) {
            int r = 21 + SEG - 1 - k;
#pragma unroll
            for (int c = 0; c < NCLS; ++c) {
                unsigned dv = (pk[c][r >> 2] >> ((r & 3) * 8)) & 0xffu;
                vneg[((size_t)(b * NCLS + c) * HH + hh) * WW + w] =
                    (unsigned char)umin32(dv, u[c]);
            }
        }
    }
}

// ---------------------------------------------------------------------------
// Kernel B: one BLOCK (4 waves) per row; wave w owns classes {w, w+4, ...}.
// r15 base + PAIRWISE CLASS ILP: two classes per scheduling region (6
// ds_read_b128 + 224 independent packed ops + ONE combined vote), so the
// ds_read->minplus->vote chain of class a overlaps class b. Tail class
// (waves 0..2) single. All r15 lessons kept: overlay merge, batched stage,
// deferred outer loads, 64-cell scatter atomic, no fences, no min-waves bound.
// ---------------------------------------------------------------------------
__global__ __launch_bounds__(256)
void kB_main(const float* __restrict__ logits,
             const unsigned char* __restrict__ vneg,
             unsigned long long* __restrict__ acc) {
    __shared__ __align__(16) unsigned smem[NCLS * 280];   // 21280 B, stage+merge
    int tid = threadIdx.x;
    int L = tid & 63;
    int wid = tid >> 6;
    int bh = blockIdx.x;               // row 0..2047
    int b = bh >> 8;
    int h = bh & 255;

    // merge-phase overlay (valid only after the post-compute barrier)
    float (*sNum)[256] = (float (*)[256])smem;                       // [4][256]
    float (*sDen)[256] = (float (*)[256])(smem + 1024);
    float (*sEt)[256]  = (float (*)[256])(smem + 2048);
    unsigned short (*sM2)[256] = (unsigned short (*)[256])(smem + 3072);
    float* wsum = (float*)(smem + 3584);

#define SQx(x) ((unsigned)((x) * (x)))
#define PK2(a, bq) (SQx(a) | (SQx(bq) << 16))
    const unsigned CE[21] = {
        PK2(-20,-19), PK2(-18,-17), PK2(-16,-15), PK2(-14,-13), PK2(-12,-11),
        PK2(-10,-9),  PK2(-8,-7),   PK2(-6,-5),   PK2(-4,-3),   PK2(-2,-1),
        PK2(0,1),     PK2(2,3),     PK2(4,5),     PK2(6,7),     PK2(8,9),
        PK2(10,11),   PK2(12,13),   PK2(14,15),   PK2(16,17),   PK2(18,19),
        PK2(20,21) };
    const unsigned CO[21] = {
        PK2(-21,-20), PK2(-19,-18), PK2(-17,-16), PK2(-15,-14), PK2(-13,-12),
        PK2(-11,-10), PK2(-9,-8),   PK2(-7,-6),   PK2(-5,-4),   PK2(-3,-2),
        PK2(-1,0),    PK2(1,2),     PK2(3,4),     PK2(5,6),     PK2(7,8),
        PK2(9,10),    PK2(11,12),   PK2(13,14),   PK2(15,16),   PK2(17,18),
        PK2(19,20) };
#undef PK2
#undef SQx

    const unsigned HALO2 = 441u | (441u << 16);
    const float* lroww = &logits[((size_t)(b * NCLS + wid) * HH + h) * WW + 8 * L];
    int nc = (wid < 3) ? 5 : 4;

    // ---- wave-local stage, batched loads ----
    uint2 v8s[5];
#pragma unroll
    for (int i = 0; i < 5; ++i)
        if (i < nc)
            v8s[i] = ((const uint2*)vneg)
                [((size_t)(b * NCLS + wid + 4 * i) * HH + h) * 64 + L];
#pragma unroll
    for (int i = 0; i < 5; ++i)
        if (i < nc) {
            int c = wid + 4 * i;
            uint4 wq;
            sq8(v8s[i].x, wq.x, wq.y);
            sq8(v8s[i].y, wq.z, wq.w);
            ((uint4*)smem)[c * WPC + L + 3] = wq;          // dwords k=4L+12..15
            if (L < 12) smem[c * 280 + L] = HALO2;         // k=0..11
            if (L >= 52) smem[c * 280 + 216 + L] = HALO2;  // k=268..279
        }

    float den[8], num[8], et[8];
    unsigned m2[8];
#pragma unroll
    for (int p = 0; p < 8; ++p) { den[p]=0.f; num[p]=0.f; et[p]=0.f; m2[p]=0xFFFFu; }

    // ---- pairwise class loop: classes (wid+8p, wid+8p+4) ----
#pragma unroll 1
    for (int p = 0; p < 2; ++p) {
        int ia = 2 * p, ib = 2 * p + 1;
        int ca = wid + 4 * ia, cb = wid + 4 * ib;
        const float* la = lroww + (size_t)(4 * ia) * (HH * WW);
        const float* lb = lroww + (size_t)(4 * ib) * (HH * WW);
        float4 fa0 = *(const float4*)la, fa1 = *(const float4*)(la + 4);
        float4 fb0 = *(const float4*)lb, fb1 = *(const float4*)(lb + 4);

        const uint4* bpa = (const uint4*)smem + ca * WPC + L;
        const uint4* bpb = (const uint4*)smem + cb * WPC + L;
        unsigned Wa[28], Wb[28], aea[4], aoa[4], aeb[4], aob[4];
        center_band(bpa, Wa, aea, aoa, CE, CO);
        center_band(bpb, Wb, aeb, aob, CE, CO);

        unsigned mx = pk_maxv(vote8(aea, aoa), vote8(aeb, aob));
        if (!__all(mx <= (49u | (49u << 16)))) {
            outer_band(bpa, Wa, aea, aoa, CE, CO);
            outer_band(bpb, Wb, aeb, aob, CE, CO);
        }
        epilogue(aea, aoa, fa0, fa1, den, num, et, m2);
        epilogue(aeb, aob, fb0, fb1, den, num, et, m2);
    }
    // ---- tail class (waves 0..2 only; wave-uniform branch) ----
    if (nc == 5) {
        const float* lt = lroww + (size_t)16 * (HH * WW);
        float4 f0 = *(const float4*)lt, f1 = *(const float4*)(lt + 4);
        const uint4* bpt = (const uint4*)smem + (wid + 16) * WPC + L;
        unsigned Wt[28], ae[4], ao[4];
        center_band(bpt, Wt, ae, ao, CE, CO);
        if (!__all(vote8(ae, ao) <= (49u | (49u << 16))))
            outer_band(bpt, Wt, ae, ao, CE, CO);
        epilogue(ae, ao, f0, f1, den, num, et, m2);
    }

    // ---- two-pass merge, OVERLAID on the stage buffer ----
    __syncthreads();   // all waves done reading stage LDS; safe to overwrite
    float vsum = 0.f;
#pragma unroll
    for (int pass = 0; pass < 2; ++pass) {
        if ((L >> 5) == pass) {                 // lanes owning this half-row
            int base = 8 * (L & 31);
            *(float4*)&sNum[wid][base]     = (float4){num[0], num[1], num[2], num[3]};
            *(float4*)&sNum[wid][base + 4] = (float4){num[4], num[5], num[6], num[7]};
            *(float4*)&sDen[wid][base]     = (float4){den[0], den[1], den[2], den[3]};
            *(float4*)&sDen[wid][base + 4] = (float4){den[4], den[5], den[6], den[7]};
            *(float4*)&sEt[wid][base]      = (float4){et[0], et[1], et[2], et[3]};
            *(float4*)&sEt[wid][base + 4]  = (float4){et[4], et[5], et[6], et[7]};
            uint4 mq;
            mq.x = m2[0] | (m2[1] << 16); mq.y = m2[2] | (m2[3] << 16);
            mq.z = m2[4] | (m2[5] << 16); mq.w = m2[6] | (m2[7] << 16);
            *(uint4*)&sM2[wid][base] = mq;
        }
        __syncthreads();
        {
            float N = sNum[0][tid] + sNum[1][tid] + sNum[2][tid] + sNum[3][tid];
            float D = sDen[0][tid] + sDen[1][tid] + sDen[2][tid] + sDen[3][tid];
            float E = sEt[0][tid] + sEt[1][tid] + sEt[2][tid] + sEt[3][tid];
            unsigned M = umin32(umin32((unsigned)sM2[0][tid], (unsigned)sM2[1][tid]),
                                umin32((unsigned)sM2[2][tid], (unsigned)sM2[3][tid]));
            vsum += (N - E * fsqrt_fast((float)umin32(M, CAP2))) / D;
        }
        __syncthreads();                        // before next pass overwrites
    }

#pragma unroll
    for (int off = 32; off >= 1; off >>= 1) vsum += __shfl_down(vsum, off);
    if (L == 0) wsum[wid] = vsum;
    __syncthreads();
    if (tid == 0) {
        float s = (wsum[0] + wsum[1]) + (wsum[2] + wsum[3]);
        // fixed-point 2^36 with /20 folded in; integer atomic => deterministic
        double q = (double)s * (68719476736.0 / 20.0);
        atomicAdd(&acc[bh & 63], (unsigned long long)(long long)q);
    }
}

__global__ void kC_final(const unsigned long long* __restrict__ acc,
                         float* __restrict__ out) {
    long long iv = 0;
    for (int i = 0; i < 64; ++i) iv += (long long)acc[i];
    double v = (double)iv / 68719476736.0;
    out[0] = (float)(v / (double)((size_t)BB * HH * WW));
}

extern "C" void kernel_launch(void* const* d_in, const int* in_sizes, int n_in,
                              void* d_out, int out_size, void* d_ws, size_t ws_size,
                              hipStream_t stream) {
    const float* logits = (const float*)d_in[0];
    const int* targ = (const int*)d_in[1];
    unsigned char* wsb = (unsigned char*)d_ws;
    unsigned long long* acc = (unsigned long long*)wsb;       // [0,512): 64 cells
    unsigned char* vneg = wsb + 1024;                         // 19.9 MB u8

    kA_vert<<<512, 256, 0, stream>>>(targ, vneg, acc);        // zeroes acc[64]
    kB_main<<<BB * HH, 256, 0, stream>>>(logits, vneg, acc);
    kC_final<<<1, 1, 0, stream>>>(acc, (float*)d_out);
}

// Round 18
// 55.986 us; speedup vs baseline: 1.1156x; 1.0362x over previous
//
#include <hip/hip_runtime.h>
#include <hip/hip_bf16.h>
#include <math.h>

// logits [8,19,256,512] f32, targets [8,256,512] int32
// R=20 truncated EDT, loss = mean_b sum_c mean_hw probs*sdf
#define NCLS 19
#define BB   8
#define HH   256
#define WW   512
#define CAP2 400u     // R^2; any value >= 400 caps identically
#define SEG  8        // rows per kA segment
#define WPC  70       // uint4 per class row in LDS (280 dwords: halo12+256+halo12)

typedef unsigned short u16x2 __attribute__((ext_vector_type(2)));

static __device__ __forceinline__ unsigned umin32(unsigned a, unsigned b) { return a < b ? a : b; }
static __device__ __forceinline__ float fsqrt_fast(float x) { return __builtin_amdgcn_sqrtf(x); }

static __device__ __forceinline__ unsigned pk_add_s(unsigned v, unsigned c) {
    unsigned d; asm("v_pk_add_u16 %0, %1, %2" : "=v"(d) : "s"(c), "v"(v)); return d;
}
static __device__ __forceinline__ unsigned pk_minv(unsigned a, unsigned b) {
    unsigned d; asm("v_pk_min_u16 %0, %1, %2" : "=v"(d) : "v"(a), "v"(b)); return d;
}
static __device__ __forceinline__ unsigned pk_maxv(unsigned a, unsigned b) {
    unsigned d; asm("v_pk_max_u16 %0, %1, %2" : "=v"(d) : "v"(a), "v"(b)); return d;
}
static __device__ __forceinline__ unsigned pk_hmin(unsigned a) {
    unsigned d;
    asm("v_pk_min_u16 %0, %1, %1 op_sel:[1,0] op_sel_hi:[0,1]" : "=v"(d) : "v"(a));
    return d;
}
// 4 u8 distances in x -> two packed-u16 squared words (verified r5)
static __device__ __forceinline__ void sq8(unsigned x, unsigned& w0, unsigned& w1) {
    unsigned a = x & 0x00FF00FFu;
    unsigned b = (x >> 8) & 0x00FF00FFu;
    u16x2 sa = __builtin_bit_cast(u16x2, a); sa = sa * sa;
    u16x2 sb = __builtin_bit_cast(u16x2, b); sb = sb * sb;
    unsigned ua = __builtin_bit_cast(unsigned, sa);
    unsigned ub = __builtin_bit_cast(unsigned, sb);
    w0 = __builtin_amdgcn_perm(ub, ua, 0x05040100u);
    w1 = __builtin_amdgcn_perm(ub, ua, 0x07060302u);
}

// ---------------------------------------------------------------------------
// Kernel A: vertical pass, SEG=8, CLASS-SPLIT for occupancy: each thread
// scans the same 29+29 rows but only 10 classes (half 0: classes 0-9,
// half 1: classes 9-18; class 9 duplicated -> same value stored twice,
// benign). 262144 threads = 4 waves/SIMD (was 2) at ~same total VALU.
// Block 0 lanes 0..63 zero the 64 accumulator cells.
// ---------------------------------------------------------------------------
__global__ __launch_bounds__(256)
void kA_vert(const int* __restrict__ targ, unsigned char* __restrict__ vneg,
             unsigned long long* __restrict__ acc) {
    if (blockIdx.x == 0 && threadIdx.x < 64) acc[threadIdx.x] = 0ULL;
    int gid = blockIdx.x * 256 + threadIdx.x;  // 4096 cols * 32 segs * 2 halves
    int col = gid & 4095;                      // lanes adjacent in w -> coalesced
    int seg = (gid >> 12) & 31;
    int c0 = (gid >> 17) * 9;                  // 0 or 9 (classes c0..c0+9)
    int b = col >> 9;
    int w = col & 511;
    int h0 = seg * SEG;
    const int* tp = &targ[b * HH * WW + w];

    unsigned d[10];
    unsigned pk[10][2];   // 8 rows of u8 distances per class
#pragma unroll
    for (int cc = 0; cc < 10; ++cc) { d[cc] = 21u; pk[cc][0] = 0u; pk[cc][1] = 0u; }
#pragma unroll
    for (int k = 0; k < 21 + SEG; ++k) {
        int hh = h0 - 21 + k;
        int t = -1;
        if (hh >= 0) t = tp[hh * WW];          // uniform branch (top segs only)
#pragma unroll
        for (int cc = 0; cc < 10; ++cc)
            d[cc] = (t == c0 + cc) ? 0u : d[cc] + 1u;
        if (k >= 21) {
            int r = k - 21;
#pragma unroll
            for (int cc = 0; cc < 10; ++cc)
                pk[cc][r >> 2] |= d[cc] << ((r & 3) * 8);
        }
    }
    unsigned u[10];
#pragma unroll
    for (int cc = 0; cc < 10; ++cc) u[cc] = 21u;
#pragma unroll
    for (int k = 0; k < 21 + SEG; ++k) {
        int hh = h0 + 21 + SEG - 1 - k;
        int t = -1;
        if (hh < HH) t = tp[hh * WW];          // uniform branch (bottom segs)
#pragma unroll
        for (int cc = 0; cc < 10; ++cc)
            u[cc] = (t == c0 + cc) ? 0u : u[cc] + 1u;
        if (k >= 21) {
            int r = 21 + SEG - 1 - k;          // 7..0
#pragma unroll
            for (int cc = 0; cc < 10; ++cc) {
                unsigned dv = (pk[cc][r >> 2] >> ((r & 3) * 8)) & 0xffu;
                vneg[((size_t)(b * NCLS + c0 + cc) * HH + hh) * WW + w] =
                    (unsigned char)umin32(dv, u[cc]);
            }
        }
    }
}

// ---------------------------------------------------------------------------
// Kernel B: one BLOCK (4 waves) per row; wave w owns classes {w, w+4, ...}.
// r15 body (converged: occupancy r8/r9/r14, data-path r6/r12/r13, ILP
// r15/r17, split r16 all plateau kB at ~40us vs max(VALU 19, BW 16) floor).
// Wave-local LDS stage (batched loads), 3+4 deferred ds_read_b128 window,
// cascade vote, targets-free epilogue, overlay merge, 64-cell scatter atomic.
// ---------------------------------------------------------------------------
__global__ __launch_bounds__(256)
void kB_main(const float* __restrict__ logits,
             const unsigned char* __restrict__ vneg,
             unsigned long long* __restrict__ acc) {
    __shared__ __align__(16) unsigned smem[NCLS * 280];   // 21280 B, stage+merge
    int tid = threadIdx.x;
    int L = tid & 63;
    int wid = tid >> 6;
    int bh = blockIdx.x;               // row 0..2047
    int b = bh >> 8;
    int h = bh & 255;

    // merge-phase overlay (valid only after the post-compute barrier)
    float (*sNum)[256] = (float (*)[256])smem;                       // [4][256]
    float (*sDen)[256] = (float (*)[256])(smem + 1024);
    float (*sEt)[256]  = (float (*)[256])(smem + 2048);
    unsigned short (*sM2)[256] = (unsigned short (*)[256])(smem + 3072);
    float* wsum = (float*)(smem + 3584);

#define SQx(x) ((unsigned)((x) * (x)))
#define PK2(a, bq) (SQx(a) | (SQx(bq) << 16))
    const unsigned CE[21] = {
        PK2(-20,-19), PK2(-18,-17), PK2(-16,-15), PK2(-14,-13), PK2(-12,-11),
        PK2(-10,-9),  PK2(-8,-7),   PK2(-6,-5),   PK2(-4,-3),   PK2(-2,-1),
        PK2(0,1),     PK2(2,3),     PK2(4,5),     PK2(6,7),     PK2(8,9),
        PK2(10,11),   PK2(12,13),   PK2(14,15),   PK2(16,17),   PK2(18,19),
        PK2(20,21) };
    const unsigned CO[21] = {
        PK2(-21,-20), PK2(-19,-18), PK2(-17,-16), PK2(-15,-14), PK2(-13,-12),
        PK2(-11,-10), PK2(-9,-8),   PK2(-7,-6),   PK2(-5,-4),   PK2(-3,-2),
        PK2(-1,0),    PK2(1,2),     PK2(3,4),     PK2(5,6),     PK2(7,8),
        PK2(9,10),    PK2(11,12),   PK2(13,14),   PK2(15,16),   PK2(17,18),
        PK2(19,20) };
#undef PK2
#undef SQx

    const unsigned HALO2 = 441u | (441u << 16);
    const float* lroww = &logits[((size_t)(b * NCLS + wid) * HH + h) * WW + 8 * L];
    int nc = (wid < 3) ? 5 : 4;

    // ---- wave-local stage, batched loads ----
    uint2 v8s[5];
#pragma unroll
    for (int i = 0; i < 5; ++i)
        if (i < nc)
            v8s[i] = ((const uint2*)vneg)
                [((size_t)(b * NCLS + wid + 4 * i) * HH + h) * 64 + L];
#pragma unroll
    for (int i = 0; i < 5; ++i)
        if (i < nc) {
            int c = wid + 4 * i;
            uint4 wq;
            sq8(v8s[i].x, wq.x, wq.y);
            sq8(v8s[i].y, wq.z, wq.w);
            ((uint4*)smem)[c * WPC + L + 3] = wq;          // dwords k=4L+12..15
            if (L < 12) smem[c * 280 + L] = HALO2;         // k=0..11
            if (L >= 52) smem[c * 280 + 216 + L] = HALO2;  // k=268..279
        }

    float den[8], num[8], et[8];
    unsigned m2[8];
#pragma unroll
    for (int p = 0; p < 8; ++p) { den[p]=0.f; num[p]=0.f; et[p]=0.f; m2[p]=0xFFFFu; }

    float4 f0n = *(const float4*)lroww;
    float4 f1n = *(const float4*)(lroww + 4);

#pragma unroll 1
    for (int i = 0; i < nc; ++i) {
        int c = wid + 4 * i;
        float4 f0 = f0n, f1 = f1n;
        if (i + 1 < nc) {
            const float* ln = lroww + (size_t)(i + 1) * 4 * (HH * WW);
            f0n = *(const float4*)ln;
            f1n = *(const float4*)(ln + 4);
        }

        // center window: only q2,q3,q4 (dwords W[8..19]) needed for m=7..13
        const uint4* basep = (const uint4*)smem + c * WPC + L;
        uint4 q2 = basep[2], q3 = basep[3], q4 = basep[4];
        unsigned W[28];
        W[8]=q2.x;  W[9]=q2.y;  W[10]=q2.z; W[11]=q2.w;
        W[12]=q3.x; W[13]=q3.y; W[14]=q3.z; W[15]=q3.w;
        W[16]=q4.x; W[17]=q4.y; W[18]=q4.z; W[19]=q4.w;

        unsigned ae[4], ao[4];
#pragma unroll
        for (int r = 0; r < 4; ++r) { ae[r] = 0xFFFFFFFFu; ao[r] = 0xFFFFFFFFu; }

        // center band m=7..13 -> W[9..18] only
#pragma unroll
        for (int r = 0; r < 4; ++r)
#pragma unroll
            for (int m = 7; m <= 13; ++m) {
                ae[r] = pk_minv(ae[r], pk_add_s(W[r + m + 2], CE[m]));
                ao[r] = pk_minv(ao[r], pk_add_s(W[r + m + 2], CO[m]));
            }

        unsigned mx = pk_maxv(pk_maxv(pk_maxv(pk_hmin(ae[0]), pk_hmin(ao[0])),
                                      pk_maxv(pk_hmin(ae[1]), pk_hmin(ao[1]))),
                              pk_maxv(pk_maxv(pk_hmin(ae[2]), pk_hmin(ao[2])),
                                      pk_maxv(pk_hmin(ae[3]), pk_hmin(ao[3]))));
        if (!__all(mx <= (49u | (49u << 16)))) {
            // outer bands need W[2..11] and W[16..25]: load q0,q1,q5,q6 now
            uint4 q0 = basep[0], q1 = basep[1], q5 = basep[5], q6 = basep[6];
            W[0]=q0.x;  W[1]=q0.y;  W[2]=q0.z;  W[3]=q0.w;
            W[4]=q1.x;  W[5]=q1.y;  W[6]=q1.z;  W[7]=q1.w;
            W[20]=q5.x; W[21]=q5.y; W[22]=q5.z; W[23]=q5.w;
            W[24]=q6.x; W[25]=q6.y; W[26]=q6.z; W[27]=q6.w;
#pragma unroll
            for (int r = 0; r < 4; ++r) {
#pragma unroll
                for (int m = 0; m <= 6; ++m) {
                    ae[r] = pk_minv(ae[r], pk_add_s(W[r + m + 2], CE[m]));
                    ao[r] = pk_minv(ao[r], pk_add_s(W[r + m + 2], CO[m]));
                }
#pragma unroll
                for (int m = 14; m <= 20; ++m) {
                    ae[r] = pk_minv(ae[r], pk_add_s(W[r + m + 2], CE[m]));
                    ao[r] = pk_minv(ao[r], pk_add_s(W[r + m + 2], CO[m]));
                }
            }
        }

        float fx[8] = {f0.x, f0.y, f0.z, f0.w, f1.x, f1.y, f1.z, f1.w};
#pragma unroll
        for (int r = 0; r < 4; ++r) {
            unsigned nd0 = pk_hmin(ae[r]) & 0xFFFFu;   // px 8L+2r
            unsigned nd1 = pk_hmin(ao[r]) & 0xFFFFu;   // px 8L+2r+1
            float e0 = __expf(fx[2 * r]), e1 = __expf(fx[2 * r + 1]);
            den[2 * r] += e0; den[2 * r + 1] += e1;
            float s0 = fsqrt_fast((float)umin32(nd0, CAP2));
            float s1 = fsqrt_fast((float)umin32(nd1, CAP2));
            num[2 * r]     += e0 * s0;     // target term: e*sqrt(0)=0, self-excluded
            num[2 * r + 1] += e1 * s1;
            bool z0 = (nd0 == 0), z1 = (nd1 == 0);
            et[2 * r]     = z0 ? e0 : et[2 * r];
            et[2 * r + 1] = z1 ? e1 : et[2 * r + 1];
            m2[2 * r]     = umin32(m2[2 * r],     z0 ? 0xFFFFu : nd0);
            m2[2 * r + 1] = umin32(m2[2 * r + 1], z1 ? 0xFFFFu : nd1);
        }
    }

    // ---- two-pass merge, OVERLAID on the stage buffer ----
    __syncthreads();   // all waves done reading stage LDS; safe to overwrite
    float vsum = 0.f;
#pragma unroll
    for (int pass = 0; pass < 2; ++pass) {
        if ((L >> 5) == pass) {                 // lanes owning this half-row
            int base = 8 * (L & 31);
            *(float4*)&sNum[wid][base]     = (float4){num[0], num[1], num[2], num[3]};
            *(float4*)&sNum[wid][base + 4] = (float4){num[4], num[5], num[6], num[7]};
            *(float4*)&sDen[wid][base]     = (float4){den[0], den[1], den[2], den[3]};
            *(float4*)&sDen[wid][base + 4] = (float4){den[4], den[5], den[6], den[7]};
            *(float4*)&sEt[wid][base]      = (float4){et[0], et[1], et[2], et[3]};
            *(float4*)&sEt[wid][base + 4]  = (float4){et[4], et[5], et[6], et[7]};
            uint4 mq;
            mq.x = m2[0] | (m2[1] << 16); mq.y = m2[2] | (m2[3] << 16);
            mq.z = m2[4] | (m2[5] << 16); mq.w = m2[6] | (m2[7] << 16);
            *(uint4*)&sM2[wid][base] = mq;
        }
        __syncthreads();
        {
            float N = sNum[0][tid] + sNum[1][tid] + sNum[2][tid] + sNum[3][tid];
            float D = sDen[0][tid] + sDen[1][tid] + sDen[2][tid] + sDen[3][tid];
            float E = sEt[0][tid] + sEt[1][tid] + sEt[2][tid] + sEt[3][tid];
            unsigned M = umin32(umin32((unsigned)sM2[0][tid], (unsigned)sM2[1][tid]),
                                umin32((unsigned)sM2[2][tid], (unsigned)sM2[3][tid]));
            vsum += (N - E * fsqrt_fast((float)umin32(M, CAP2))) / D;
        }
        __syncthreads();                        // before next pass overwrites
    }

#pragma unroll
    for (int off = 32; off >= 1; off >>= 1) vsum += __shfl_down(vsum, off);
    if (L == 0) wsum[wid] = vsum;
    __syncthreads();
    if (tid == 0) {
        float s = (wsum[0] + wsum[1]) + (wsum[2] + wsum[3]);
        // fixed-point 2^36 with /20 folded in; integer atomic => deterministic
        double q = (double)s * (68719476736.0 / 20.0);
        atomicAdd(&acc[bh & 63], (unsigned long long)(long long)q);
    }
}

__global__ void kC_final(const unsigned long long* __restrict__ acc,
                         float* __restrict__ out) {
    long long iv = 0;
    for (int i = 0; i < 64; ++i) iv += (long long)acc[i];
    double v = (double)iv / 68719476736.0;
    out[0] = (float)(v / (double)((size_t)BB * HH * WW));
}

extern "C" void kernel_launch(void* const* d_in, const int* in_sizes, int n_in,
                              void* d_out, int out_size, void* d_ws, size_t ws_size,
                              hipStream_t stream) {
    const float* logits = (const float*)d_in[0];
    const int* targ = (const int*)d_in[1];
    unsigned char* wsb = (unsigned char*)d_ws;
    unsigned long long* acc = (unsigned long long*)wsb;       // [0,512): 64 cells
    unsigned char* vneg = wsb + 1024;                         // 19.9 MB u8

    kA_vert<<<1024, 256, 0, stream>>>(targ, vneg, acc);       // 262144 threads
    kB_main<<<BB * HH, 256, 0, stream>>>(logits, vneg, acc);
    kC_final<<<1, 1, 0, stream>>>(acc, (float*)d_out);
}

// Round 19
// 54.177 us; speedup vs baseline: 1.1529x; 1.0334x over previous
//
#include <hip/hip_runtime.h>
#include <hip/hip_bf16.h>
#include <math.h>

// logits [8,19,256,512] f32, targets [8,256,512] int32
// R=20 truncated EDT, loss = mean_b sum_c mean_hw probs*sdf
#define NCLS 19
#define BB   8
#define HH   256
#define WW   512
#define CAP2 400u     // R^2; any value >= 400 caps identically
#define SEG  8        // rows per kA segment
#define WPC  70       // uint4 per class row in LDS (280 dwords: halo12+256+halo12)

typedef unsigned short u16x2 __attribute__((ext_vector_type(2)));

static __device__ __forceinline__ unsigned umin32(unsigned a, unsigned b) { return a < b ? a : b; }
static __device__ __forceinline__ float fsqrt_fast(float x) { return __builtin_amdgcn_sqrtf(x); }

static __device__ __forceinline__ unsigned pk_add_s(unsigned v, unsigned c) {
    unsigned d; asm("v_pk_add_u16 %0, %1, %2" : "=v"(d) : "s"(c), "v"(v)); return d;
}
static __device__ __forceinline__ unsigned pk_minv(unsigned a, unsigned b) {
    unsigned d; asm("v_pk_min_u16 %0, %1, %2" : "=v"(d) : "v"(a), "v"(b)); return d;
}
static __device__ __forceinline__ unsigned pk_maxv(unsigned a, unsigned b) {
    unsigned d; asm("v_pk_max_u16 %0, %1, %2" : "=v"(d) : "v"(a), "v"(b)); return d;
}
static __device__ __forceinline__ unsigned pk_hmin(unsigned a) {
    unsigned d;
    asm("v_pk_min_u16 %0, %1, %1 op_sel:[1,0] op_sel_hi:[0,1]" : "=v"(d) : "v"(a));
    return d;
}
// 4 u8 distances in x -> two packed-u16 squared words (verified r5)
static __device__ __forceinline__ void sq8(unsigned x, unsigned& w0, unsigned& w1) {
    unsigned a = x & 0x00FF00FFu;
    unsigned b = (x >> 8) & 0x00FF00FFu;
    u16x2 sa = __builtin_bit_cast(u16x2, a); sa = sa * sa;
    u16x2 sb = __builtin_bit_cast(u16x2, b); sb = sb * sb;
    unsigned ua = __builtin_bit_cast(unsigned, sa);
    unsigned ub = __builtin_bit_cast(unsigned, sb);
    w0 = __builtin_amdgcn_perm(ub, ua, 0x05040100u);
    w1 = __builtin_amdgcn_perm(ub, ua, 0x07060302u);
}

// ---------------------------------------------------------------------------
// Kernel A: vertical pass, SEG=8, class-split (10 classes/thread, class 9
// duplicated across halves - benign double-write of identical value).
// 262144 threads = 4 waves/SIMD. Block 0 zeroes the 64 accumulator cells.
// ---------------------------------------------------------------------------
__global__ __launch_bounds__(256)
void kA_vert(const int* __restrict__ targ, unsigned char* __restrict__ vneg,
             unsigned long long* __restrict__ acc) {
    if (blockIdx.x == 0 && threadIdx.x < 64) acc[threadIdx.x] = 0ULL;
    int gid = blockIdx.x * 256 + threadIdx.x;  // 4096 cols * 32 segs * 2 halves
    int col = gid & 4095;                      // lanes adjacent in w -> coalesced
    int seg = (gid >> 12) & 31;
    int c0 = (gid >> 17) * 9;                  // 0 or 9 (classes c0..c0+9)
    int b = col >> 9;
    int w = col & 511;
    int h0 = seg * SEG;
    const int* tp = &targ[b * HH * WW + w];

    unsigned d[10];
    unsigned pk[10][2];   // 8 rows of u8 distances per class
#pragma unroll
    for (int cc = 0; cc < 10; ++cc) { d[cc] = 21u; pk[cc][0] = 0u; pk[cc][1] = 0u; }
#pragma unroll
    for (int k = 0; k < 21 + SEG; ++k) {
        int hh = h0 - 21 + k;
        int t = -1;
        if (hh >= 0) t = tp[hh * WW];          // uniform branch (top segs only)
#pragma unroll
        for (int cc = 0; cc < 10; ++cc)
            d[cc] = (t == c0 + cc) ? 0u : d[cc] + 1u;
        if (k >= 21) {
            int r = k - 21;
#pragma unroll
            for (int cc = 0; cc < 10; ++cc)
                pk[cc][r >> 2] |= d[cc] << ((r & 3) * 8);
        }
    }
    unsigned u[10];
#pragma unroll
    for (int cc = 0; cc < 10; ++cc) u[cc] = 21u;
#pragma unroll
    for (int k = 0; k < 21 + SEG; ++k) {
        int hh = h0 + 21 + SEG - 1 - k;
        int t = -1;
        if (hh < HH) t = tp[hh * WW];          // uniform branch (bottom segs)
#pragma unroll
        for (int cc = 0; cc < 10; ++cc)
            u[cc] = (t == c0 + cc) ? 0u : u[cc] + 1u;
        if (k >= 21) {
            int r = 21 + SEG - 1 - k;          // 7..0
#pragma unroll
            for (int cc = 0; cc < 10; ++cc) {
                unsigned dv = (pk[cc][r >> 2] >> ((r & 3) * 8)) & 0xffu;
                vneg[((size_t)(b * NCLS + c0 + cc) * HH + hh) * WW + w] =
                    (unsigned char)umin32(dv, u[cc]);
            }
        }
    }
}

// ---------------------------------------------------------------------------
// Kernel B: one BLOCK (4 waves) per row; wave w owns classes {w, w+4, ...}.
// r18 body + 2-DEEP logits prefetch: per-class body ~450cyc < load latency
// ~900cyc, so 1-deep prefetch left ~450cyc stall/class (measured: 15us busy
// vs 40us wall). Issuing class i+2's loads at iteration i covers latency
// with two bodies. +8 VGPR, stays within 8 waves/SIMD budget.
// ---------------------------------------------------------------------------
__global__ __launch_bounds__(256)
void kB_main(const float* __restrict__ logits,
             const unsigned char* __restrict__ vneg,
             unsigned long long* __restrict__ acc) {
    __shared__ __align__(16) unsigned smem[NCLS * 280];   // 21280 B, stage+merge
    int tid = threadIdx.x;
    int L = tid & 63;
    int wid = tid >> 6;
    int bh = blockIdx.x;               // row 0..2047
    int b = bh >> 8;
    int h = bh & 255;

    // merge-phase overlay (valid only after the post-compute barrier)
    float (*sNum)[256] = (float (*)[256])smem;                       // [4][256]
    float (*sDen)[256] = (float (*)[256])(smem + 1024);
    float (*sEt)[256]  = (float (*)[256])(smem + 2048);
    unsigned short (*sM2)[256] = (unsigned short (*)[256])(smem + 3072);
    float* wsum = (float*)(smem + 3584);

#define SQx(x) ((unsigned)((x) * (x)))
#define PK2(a, bq) (SQx(a) | (SQx(bq) << 16))
    const unsigned CE[21] = {
        PK2(-20,-19), PK2(-18,-17), PK2(-16,-15), PK2(-14,-13), PK2(-12,-11),
        PK2(-10,-9),  PK2(-8,-7),   PK2(-6,-5),   PK2(-4,-3),   PK2(-2,-1),
        PK2(0,1),     PK2(2,3),     PK2(4,5),     PK2(6,7),     PK2(8,9),
        PK2(10,11),   PK2(12,13),   PK2(14,15),   PK2(16,17),   PK2(18,19),
        PK2(20,21) };
    const unsigned CO[21] = {
        PK2(-21,-20), PK2(-19,-18), PK2(-17,-16), PK2(-15,-14), PK2(-13,-12),
        PK2(-11,-10), PK2(-9,-8),   PK2(-7,-6),   PK2(-5,-4),   PK2(-3,-2),
        PK2(-1,0),    PK2(1,2),     PK2(3,4),     PK2(5,6),     PK2(7,8),
        PK2(9,10),    PK2(11,12),   PK2(13,14),   PK2(15,16),   PK2(17,18),
        PK2(19,20) };
#undef PK2
#undef SQx

    const unsigned HALO2 = 441u | (441u << 16);
    const float* lroww = &logits[((size_t)(b * NCLS + wid) * HH + h) * WW + 8 * L];
    int nc = (wid < 3) ? 5 : 4;

    // ---- wave-local stage, batched loads ----
    uint2 v8s[5];
#pragma unroll
    for (int i = 0; i < 5; ++i)
        if (i < nc)
            v8s[i] = ((const uint2*)vneg)
                [((size_t)(b * NCLS + wid + 4 * i) * HH + h) * 64 + L];
#pragma unroll
    for (int i = 0; i < 5; ++i)
        if (i < nc) {
            int c = wid + 4 * i;
            uint4 wq;
            sq8(v8s[i].x, wq.x, wq.y);
            sq8(v8s[i].y, wq.z, wq.w);
            ((uint4*)smem)[c * WPC + L + 3] = wq;          // dwords k=4L+12..15
            if (L < 12) smem[c * 280 + L] = HALO2;         // k=0..11
            if (L >= 52) smem[c * 280 + 216 + L] = HALO2;  // k=268..279
        }

    float den[8], num[8], et[8];
    unsigned m2[8];
#pragma unroll
    for (int p = 0; p < 8; ++p) { den[p]=0.f; num[p]=0.f; et[p]=0.f; m2[p]=0xFFFFu; }

    // 2-deep logits prefetch pipeline
    float4 f0n = *(const float4*)lroww;                    // class i=0
    float4 f1n = *(const float4*)(lroww + 4);
    const float* l1 = lroww + (size_t)4 * (HH * WW);       // class i=1 (nc>=4 always)
    float4 f0n2 = *(const float4*)l1;
    float4 f1n2 = *(const float4*)(l1 + 4);

#pragma unroll 1
    for (int i = 0; i < nc; ++i) {
        int c = wid + 4 * i;
        float4 f0 = f0n, f1 = f1n;
        f0n = f0n2; f1n = f1n2;
        {   // issue class i+2's loads now (2 bodies ahead of use)
            int ipre = (i + 2 < nc) ? (i + 2) : i;         // clamped: in-bounds
            const float* ln = lroww + (size_t)ipre * 4 * (HH * WW);
            f0n2 = *(const float4*)ln;
            f1n2 = *(const float4*)(ln + 4);
        }

        // center window: only q2,q3,q4 (dwords W[8..19]) needed for m=7..13
        const uint4* basep = (const uint4*)smem + c * WPC + L;
        uint4 q2 = basep[2], q3 = basep[3], q4 = basep[4];
        unsigned W[28];
        W[8]=q2.x;  W[9]=q2.y;  W[10]=q2.z; W[11]=q2.w;
        W[12]=q3.x; W[13]=q3.y; W[14]=q3.z; W[15]=q3.w;
        W[16]=q4.x; W[17]=q4.y; W[18]=q4.z; W[19]=q4.w;

        unsigned ae[4], ao[4];
#pragma unroll
        for (int r = 0; r < 4; ++r) { ae[r] = 0xFFFFFFFFu; ao[r] = 0xFFFFFFFFu; }

        // center band m=7..13 -> W[9..18] only
#pragma unroll
        for (int r = 0; r < 4; ++r)
#pragma unroll
            for (int m = 7; m <= 13; ++m) {
                ae[r] = pk_minv(ae[r], pk_add_s(W[r + m + 2], CE[m]));
                ao[r] = pk_minv(ao[r], pk_add_s(W[r + m + 2], CO[m]));
            }

        unsigned mx = pk_maxv(pk_maxv(pk_maxv(pk_hmin(ae[0]), pk_hmin(ao[0])),
                                      pk_maxv(pk_hmin(ae[1]), pk_hmin(ao[1]))),
                              pk_maxv(pk_maxv(pk_hmin(ae[2]), pk_hmin(ao[2])),
                                      pk_maxv(pk_hmin(ae[3]), pk_hmin(ao[3]))));
        if (!__all(mx <= (49u | (49u << 16)))) {
            // outer bands need W[2..11] and W[16..25]: load q0,q1,q5,q6 now
            uint4 q0 = basep[0], q1 = basep[1], q5 = basep[5], q6 = basep[6];
            W[0]=q0.x;  W[1]=q0.y;  W[2]=q0.z;  W[3]=q0.w;
            W[4]=q1.x;  W[5]=q1.y;  W[6]=q1.z;  W[7]=q1.w;
            W[20]=q5.x; W[21]=q5.y; W[22]=q5.z; W[23]=q5.w;
            W[24]=q6.x; W[25]=q6.y; W[26]=q6.z; W[27]=q6.w;
#pragma unroll
            for (int r = 0; r < 4; ++r) {
#pragma unroll
                for (int m = 0; m <= 6; ++m) {
                    ae[r] = pk_minv(ae[r], pk_add_s(W[r + m + 2], CE[m]));
                    ao[r] = pk_minv(ao[r], pk_add_s(W[r + m + 2], CO[m]));
                }
#pragma unroll
                for (int m = 14; m <= 20; ++m) {
                    ae[r] = pk_minv(ae[r], pk_add_s(W[r + m + 2], CE[m]));
                    ao[r] = pk_minv(ao[r], pk_add_s(W[r + m + 2], CO[m]));
                }
            }
        }

        float fx[8] = {f0.x, f0.y, f0.z, f0.w, f1.x, f1.y, f1.z, f1.w};
#pragma unroll
        for (int r = 0; r < 4; ++r) {
            unsigned nd0 = pk_hmin(ae[r]) & 0xFFFFu;   // px 8L+2r
            unsigned nd1 = pk_hmin(ao[r]) & 0xFFFFu;   // px 8L+2r+1
            float e0 = __expf(fx[2 * r]), e1 = __expf(fx[2 * r + 1]);
            den[2 * r] += e0; den[2 * r + 1] += e1;
            float s0 = fsqrt_fast((float)umin32(nd0, CAP2));
            float s1 = fsqrt_fast((float)umin32(nd1, CAP2));
            num[2 * r]     += e0 * s0;     // target term: e*sqrt(0)=0, self-excluded
            num[2 * r + 1] += e1 * s1;
            bool z0 = (nd0 == 0), z1 = (nd1 == 0);
            et[2 * r]     = z0 ? e0 : et[2 * r];
            et[2 * r + 1] = z1 ? e1 : et[2 * r + 1];
            m2[2 * r]     = umin32(m2[2 * r],     z0 ? 0xFFFFu : nd0);
            m2[2 * r + 1] = umin32(m2[2 * r + 1], z1 ? 0xFFFFu : nd1);
        }
    }

    // ---- two-pass merge, OVERLAID on the stage buffer ----
    __syncthreads();   // all waves done reading stage LDS; safe to overwrite
    float vsum = 0.f;
#pragma unroll
    for (int pass = 0; pass < 2; ++pass) {
        if ((L >> 5) == pass) {                 // lanes owning this half-row
            int base = 8 * (L & 31);
            *(float4*)&sNum[wid][base]     = (float4){num[0], num[1], num[2], num[3]};
            *(float4*)&sNum[wid][base + 4] = (float4){num[4], num[5], num[6], num[7]};
            *(float4*)&sDen[wid][base]     = (float4){den[0], den[1], den[2], den[3]};
            *(float4*)&sDen[wid][base + 4] = (float4){den[4], den[5], den[6], den[7]};
            *(float4*)&sEt[wid][base]      = (float4){et[0], et[1], et[2], et[3]};
            *(float4*)&sEt[wid][base + 4]  = (float4){et[4], et[5], et[6], et[7]};
            uint4 mq;
            mq.x = m2[0] | (m2[1] << 16); mq.y = m2[2] | (m2[3] << 16);
            mq.z = m2[4] | (m2[5] << 16); mq.w = m2[6] | (m2[7] << 16);
            *(uint4*)&sM2[wid][base] = mq;
        }
        __syncthreads();
        {
            float N = sNum[0][tid] + sNum[1][tid] + sNum[2][tid] + sNum[3][tid];
            float D = sDen[0][tid] + sDen[1][tid] + sDen[2][tid] + sDen[3][tid];
            float E = sEt[0][tid] + sEt[1][tid] + sEt[2][tid] + sEt[3][tid];
            unsigned M = umin32(umin32((unsigned)sM2[0][tid], (unsigned)sM2[1][tid]),
                                umin32((unsigned)sM2[2][tid], (unsigned)sM2[3][tid]));
            vsum += (N - E * fsqrt_fast((float)umin32(M, CAP2))) / D;
        }
        __syncthreads();                        // before next pass overwrites
    }

#pragma unroll
    for (int off = 32; off >= 1; off >>= 1) vsum += __shfl_down(vsum, off);
    if (L == 0) wsum[wid] = vsum;
    __syncthreads();
    if (tid == 0) {
        float s = (wsum[0] + wsum[1]) + (wsum[2] + wsum[3]);
        // fixed-point 2^36 with /20 folded in; integer atomic => deterministic
        double q = (double)s * (68719476736.0 / 20.0);
        atomicAdd(&acc[bh & 63], (unsigned long long)(long long)q);
    }
}

// one wave: parallel cell loads + shuffle reduce (integer = deterministic)
__global__ void kC_final(const unsigned long long* __restrict__ acc,
                         float* __restrict__ out) {
    int L = threadIdx.x;
    long long v = (long long)acc[L];
#pragma unroll
    for (int off = 32; off >= 1; off >>= 1) v += __shfl_down(v, off);
    if (L == 0) {
        double d = (double)v / 68719476736.0;
        out[0] = (float)(d / (double)((size_t)BB * HH * WW));
    }
}

extern "C" void kernel_launch(void* const* d_in, const int* in_sizes, int n_in,
                              void* d_out, int out_size, void* d_ws, size_t ws_size,
                              hipStream_t stream) {
    const float* logits = (const float*)d_in[0];
    const int* targ = (const int*)d_in[1];
    unsigned char* wsb = (unsigned char*)d_ws;
    unsigned long long* acc = (unsigned long long*)wsb;       // [0,512): 64 cells
    unsigned char* vneg = wsb + 1024;                         // 19.9 MB u8

    kA_vert<<<1024, 256, 0, stream>>>(targ, vneg, acc);       // 262144 threads
    kB_main<<<BB * HH, 256, 0, stream>>>(logits, vneg, acc);
    kC_final<<<1, 64, 0, stream>>>(acc, (float*)d_out);
}